// Round 18
// baseline (309.008 us; speedup 1.0000x reference)
//
#include <hip/hip_runtime.h>

#define HDIM 128
#define NGRAPH 64
#define INVSTD 0.99999500003749972f   // 1/sqrt(1+1e-5)
#define WTPAD 136
#define WSLOT (128 * WTPAD)
#define BKN 512                        // nodes per bucket (power of 2)
#define EPB 4096                       // edges per pass-A/B block

typedef unsigned short ushort_t;
typedef unsigned int uint_t;
typedef __attribute__((ext_vector_type(8))) short bf16x8;   // 8 bf16 = 4 VGPR
typedef __attribute__((ext_vector_type(4))) float f32x4;
typedef __attribute__((ext_vector_type(2))) _Float16 h16x2;

__device__ __forceinline__ float bf2f(uint_t u) {            // low 16 bits
    return __int_as_float((int)(u << 16));
}
__device__ __forceinline__ uint_t f2bf(float f) {            // RNE
    uint_t x = __float_as_uint(f);
    return (x + 0x7FFFu + ((x >> 16) & 1u)) >> 16;
}
__device__ __forceinline__ uint_t pack2(float a, float b) {
    return f2bf(a) | (f2bf(b) << 16);
}
__device__ __forceinline__ uint_t h2u(h16x2 h) {
    union { h16x2 h; uint_t u; } x; x.h = h; return x.u;
}
__device__ __forceinline__ h16x2 u2h(uint_t u) {
    union { h16x2 h; uint_t u; } x; x.u = u; return x.h;
}
__device__ __forceinline__ uint_t packh2(float a, float b) {
    h16x2 v; v[0] = (_Float16)a; v[1] = (_Float16)b; return h2u(v);
}
__device__ __forceinline__ ushort_t f2h(float f) {
    union { _Float16 h; ushort_t u; } x; x.h = (_Float16)f; return x.u;
}
__device__ __forceinline__ uint_t pkmax0(uint_t x) {         // packed relu: v_pk_max_f16(x, 0)
    uint_t r, z = 0;
    asm("v_pk_max_f16 %0, %1, %2" : "=v"(r) : "v"(x), "v"(z));
    return r;
}

// ---- encode: table T = x*ew + enc_b + eenc_b; hh = fp16(T)
__global__ void k_encode(const float* __restrict__ x, const float* __restrict__ ew,
                         const float* __restrict__ enb, const float* __restrict__ ebe,
                         ushort_t* __restrict__ hh, int N) {
    int tid = blockIdx.x * blockDim.x + threadIdx.x;
    int stride = gridDim.x * blockDim.x;
    int q = tid & 15;
    float4 wa = ((const float4*)ew)[2 * q];
    float4 wb = ((const float4*)ew)[2 * q + 1];
    float4 ba = ((const float4*)enb)[2 * q];
    float4 bb = ((const float4*)enb)[2 * q + 1];
    float4 ea = ((const float4*)ebe)[2 * q];
    float4 eb2 = ((const float4*)ebe)[2 * q + 1];
    ba.x += ea.x; ba.y += ea.y; ba.z += ea.z; ba.w += ea.w;
    bb.x += eb2.x; bb.y += eb2.y; bb.z += eb2.z; bb.w += eb2.w;
    int total = N * 16;
    for (int t = tid; t < total; t += stride) {
        int n = t >> 4;
        float xv = x[n];
        uint4 o;
        o.x = packh2(fmaf(xv, wa.x, ba.x), fmaf(xv, wa.y, ba.y));
        o.y = packh2(fmaf(xv, wa.z, ba.z), fmaf(xv, wa.w, ba.w));
        o.z = packh2(fmaf(xv, wb.x, bb.x), fmaf(xv, wb.y, bb.y));
        o.w = packh2(fmaf(xv, wb.z, bb.z), fmaf(xv, wb.w, bb.w));
        ((uint4*)(hh + (size_t)n * HDIM))[q] = o;
    }
}

// ---- weight prep: wtg[slot][n*WTPAD+k] = bf16(W_slot[k][n]); slots {w1_0,w2_0,w1_1,w2_1}
__global__ void k_prepw(const float* __restrict__ w1, const float* __restrict__ w2,
                        ushort_t* __restrict__ wtg) {
    int t = blockIdx.x * 256 + threadIdx.x;
    if (t >= 4 * 16384) return;
    int w = t >> 14, idx = t & 16383;
    int k = idx >> 7, n = idx & 127;
    const float* src = ((w & 1) ? w2 : w1) + (size_t)(w >> 1) * 16384;
    wtg[(size_t)w * WSLOT + n * WTPAD + k] = (ushort_t)f2bf(src[idx]);
}

// =============== CSR build: bucket counting sort, no per-edge global atomics ===============
__global__ __launch_bounds__(256) void k_cnt(const int* __restrict__ ei, int* __restrict__ btot,
                                             int nb, int E) {
    __shared__ int hist[256];
    hist[threadIdx.x] = 0;
    __syncthreads();
    int e0 = blockIdx.x * EPB;
    for (int i = threadIdx.x; i < EPB; i += 256) {
        int e = e0 + i;
        if (e < E) atomicAdd(&hist[ei[E + e] / BKN], 1);
    }
    __syncthreads();
    int c = hist[threadIdx.x];
    if (threadIdx.x < nb && c > 0) atomicAdd(&btot[threadIdx.x], c);
}

__global__ void k_bscan(const int* __restrict__ btot, int* __restrict__ segs, int nb, int E) {
    __shared__ int sm[256];
    int t = threadIdx.x;
    int v = (t < nb) ? btot[t] : 0;
    sm[t] = v;
    __syncthreads();
    #pragma unroll
    for (int off = 1; off < 256; off <<= 1) {
        int u = (t >= off) ? sm[t - off] : 0;
        __syncthreads();
        sm[t] += u;
        __syncthreads();
    }
    if (t < nb) segs[t] = sm[t] - v;
    if (t == 0) segs[nb] = E;
}

// Pass B: group edges by coarse bucket; record {s | (d&511)<<17, attr as dup fp16 pair}.
__global__ __launch_bounds__(256) void k_place0(const int* __restrict__ ei,
                                                const float* __restrict__ attr,
                                                const int* __restrict__ segs, int* cursor,
                                                int2* __restrict__ ebuf, int nb, int E) {
    __shared__ int hist[256];
    __shared__ int basev[256];
    hist[threadIdx.x] = 0;
    __syncthreads();
    int e0 = blockIdx.x * EPB;
    for (int i = threadIdx.x; i < EPB; i += 256) {
        int e = e0 + i;
        if (e < E) atomicAdd(&hist[ei[E + e] / BKN], 1);
    }
    __syncthreads();
    {
        int c = hist[threadIdx.x];
        basev[threadIdx.x] = (threadIdx.x < nb && c > 0) ? atomicAdd(&cursor[threadIdx.x], c) : 0;
        hist[threadIdx.x] = 0;          // reuse as local rank cursor
    }
    __syncthreads();
    for (int i = threadIdx.x; i < EPB; i += 256) {
        int e = e0 + i;
        if (e < E) {
            int s = ei[e], d = ei[E + e];
            float a = attr[e];
            int b = d / BKN;
            int r = atomicAdd(&hist[b], 1);
            ebuf[segs[b] + basev[b] + r] = make_int2(s | ((d & (BKN - 1)) << 17),
                                                     (int)packh2(a, a));
        }
    }
}

__global__ __launch_bounds__(256) void k_fine(const int2* __restrict__ ebuf,
                                              const int* __restrict__ segs,
                                              int2* __restrict__ epack, int* __restrict__ rs,
                                              int nb, int N, int E) {
    __shared__ int hist[BKN];
    __shared__ int cur[BKN];
    __shared__ int psum[256];
    int b = blockIdx.x;
    int d0 = b * BKN;
    int nd = min(BKN, N - d0);
    for (int i = threadIdx.x; i < BKN; i += 256) hist[i] = 0;
    __syncthreads();
    int s0 = segs[b], s1 = segs[b + 1];
    for (int e = s0 + threadIdx.x; e < s1; e += 256)
        atomicAdd(&hist[(uint_t)ebuf[e].x >> 17], 1);
    __syncthreads();
    int h0 = hist[2 * threadIdx.x], h1 = hist[2 * threadIdx.x + 1];
    psum[threadIdx.x] = h0 + h1;
    __syncthreads();
    #pragma unroll
    for (int off = 1; off < 256; off <<= 1) {
        int u = (threadIdx.x >= off) ? psum[threadIdx.x - off] : 0;
        __syncthreads();
        psum[threadIdx.x] += u;
        __syncthreads();
    }
    int pb = psum[threadIdx.x] - (h0 + h1);
    cur[2 * threadIdx.x] = pb;
    cur[2 * threadIdx.x + 1] = pb + h0;
    __syncthreads();
    for (int i = threadIdx.x; i < nd; i += 256) rs[d0 + i] = s0 + cur[i];
    if (b == nb - 1 && threadIdx.x == 0) rs[N] = E;
    __syncthreads();
    for (int e = s0 + threadIdx.x; e < s1; e += 256) {
        int2 rec = ebuf[e];
        int dl = (uint_t)rec.x >> 17;
        int r = atomicAdd(&cur[dl], 1);
        epack[s0 + r] = make_int2(rec.x & 0x1FFFF, rec.y);
    }
}

// ------- aggregation: one wave/node, 16 lanes/edge, fp16 gathers, packed-fp16 math -------
__device__ __forceinline__ void acc_edge(h16x2 acc[4], const uint4& u, h16x2 at2,
                                         const h16x2 w2[4]) {
    acc[0] += u2h(pkmax0(h2u(at2 * w2[0] + u2h(u.x))));
    acc[1] += u2h(pkmax0(h2u(at2 * w2[1] + u2h(u.y))));
    acc[2] += u2h(pkmax0(h2u(at2 * w2[2] + u2h(u.z))));
    acc[3] += u2h(pkmax0(h2u(at2 * w2[3] + u2h(u.w))));
}

__global__ __launch_bounds__(256) void k_agg(
    const ushort_t* __restrict__ hh, const int* __restrict__ rs,
    const int2* __restrict__ epack,
    const float* __restrict__ ew, const float* __restrict__ ebv,
    const float* __restrict__ epsp, ushort_t* __restrict__ zb, int N) {
    int wave = (blockIdx.x * 256 + threadIdx.x) >> 6;
    if (wave >= N) return;
    int lane = threadIdx.x & 63;
    int p = lane >> 4;          // quarter-wave: edges j ≡ p (mod 4)
    int q = lane & 15;          // features 8q..8q+7
    int n = wave;
    int beg = rs[n];
    int cntE = rs[n + 1] - beg;
    float4 wa = ((const float4*)ew)[2 * q], wb = ((const float4*)ew)[2 * q + 1];
    h16x2 w2[4];
    w2[0] = u2h(packh2(wa.x, wa.y));
    w2[1] = u2h(packh2(wa.z, wa.w));
    w2[2] = u2h(packh2(wb.x, wb.y));
    w2[3] = u2h(packh2(wb.z, wb.w));

    h16x2 acc[4], acc2[4];
    #pragma unroll
    for (int k = 0; k < 4; ++k) { acc[k] = u2h(0u); acc2[k] = u2h(0u); }
    int j = p;
    for (; j + 4 < cntE; j += 8) {
        int2 e1 = epack[beg + j];
        int2 e2 = epack[beg + j + 4];
        uint4 u1 = *(const uint4*)(hh + (size_t)e1.x * HDIM + q * 8);
        uint4 u2v = *(const uint4*)(hh + (size_t)e2.x * HDIM + q * 8);
        acc_edge(acc,  u1, u2h((uint_t)e1.y), w2);
        acc_edge(acc2, u2v, u2h((uint_t)e2.y), w2);
    }
    if (j < cntE) {
        int2 e1 = epack[beg + j];
        uint4 u1 = *(const uint4*)(hh + (size_t)e1.x * HDIM + q * 8);
        acc_edge(acc, u1, u2h((uint_t)e1.y), w2);
    }
    #pragma unroll
    for (int k = 0; k < 4; ++k) {
        h16x2 c = acc[k] + acc2[k];
        c += u2h((uint_t)__shfl_xor((int)h2u(c), 16));
        c += u2h((uint_t)__shfl_xor((int)h2u(c), 32));
        acc[k] = c;
    }
    if (p == 0) {
        float sc = 1.f + epsp[0];
        float4 ba = ((const float4*)ebv)[2 * q], bb = ((const float4*)ebv)[2 * q + 1];
        uint4 u = *(const uint4*)(hh + (size_t)n * HDIM + q * 8);
        h16x2 t0 = u2h(u.x), t1 = u2h(u.y), t2 = u2h(u.z), t3 = u2h(u.w);
        // z = sc*T[n] + agg - sc*eenc_b   (f32 epilogue, bf16 out)
        uint4 ob;
        ob.x = pack2(fmaf(sc, (float)t0[0], (float)acc[0][0]) - sc * ba.x,
                     fmaf(sc, (float)t0[1], (float)acc[0][1]) - sc * ba.y);
        ob.y = pack2(fmaf(sc, (float)t1[0], (float)acc[1][0]) - sc * ba.z,
                     fmaf(sc, (float)t1[1], (float)acc[1][1]) - sc * ba.w);
        ob.z = pack2(fmaf(sc, (float)t2[0], (float)acc[2][0]) - sc * bb.x,
                     fmaf(sc, (float)t2[1], (float)acc[2][1]) - sc * bb.y);
        ob.w = pack2(fmaf(sc, (float)t3[0], (float)acc[3][0]) - sc * bb.z,
                     fmaf(sc, (float)t3[1], (float)acc[3][1]) - sc * bb.w);
        *(uint4*)(zb + (size_t)n * HDIM + q * 8) = ob;
    }
}

// ------------- MFMA GEMM: out = epilogue(A @ W + bias), 256 rows/block -------------
// MODE 0: relu, bf16 out.  MODE 1: BN+relu.  EBF: +eenc_b.  OUT16: fp16 out (gather table).
template<int MODE, int EBF, int OUT16>
__global__ __launch_bounds__(256) void k_gemm(
    const ushort_t* __restrict__ A, const ushort_t* __restrict__ WT,
    const float* __restrict__ bias, const float* __restrict__ gam,
    const float* __restrict__ bet, const float* __restrict__ ebe,
    ushort_t* __restrict__ out, int N) {
    __shared__ ushort_t wt[128 * WTPAD];
    int tid = threadIdx.x;
    #pragma unroll
    for (int i = 0; i < 9; ++i) {           // 128*136/8 = 2176 bf16x8 chunks
        int c = i * 256 + tid;
        if (c < 2176) ((bf16x8*)wt)[c] = ((const bf16x8*)WT)[c];
    }
    __syncthreads();

    int wid = tid >> 6, lane = tid & 63;
    int ra = lane & 15, qa = lane >> 4;

    bf16x8 bfr[4][8];
    #pragma unroll
    for (int ks = 0; ks < 4; ++ks)
        #pragma unroll
        for (int nf = 0; nf < 8; ++nf)
            bfr[ks][nf] = *(const bf16x8*)&wt[(nf * 16 + ra) * WTPAD + ks * 32 + qa * 8];

    float bi[8], gg[8], be_[8], ef[8];
    #pragma unroll
    for (int nf = 0; nf < 8; ++nf) {
        int col = nf * 16 + ra;
        bi[nf] = bias[col];
        if (MODE == 1) { gg[nf] = gam[col]; be_[nf] = bet[col]; }
        if (EBF)       { ef[nf] = ebe[col]; }
    }

    bf16x8 azero;
    #pragma unroll
    for (int j = 0; j < 8; ++j) azero[j] = 0;

    #pragma unroll
    for (int it = 0; it < 4; ++it) {
        int m0 = blockIdx.x * 256 + it * 64 + wid * 16;
        int mr = m0 + ra;
        bf16x8 afr[4];
        #pragma unroll
        for (int ks = 0; ks < 4; ++ks)
            afr[ks] = (mr < N) ? *(const bf16x8*)&A[(size_t)mr * HDIM + ks * 32 + qa * 8]
                               : azero;
        f32x4 acc[8];
        #pragma unroll
        for (int nf = 0; nf < 8; ++nf)
            #pragma unroll
            for (int j = 0; j < 4; ++j) acc[nf][j] = 0.f;
        #pragma unroll
        for (int ks = 0; ks < 4; ++ks)
            #pragma unroll
            for (int nf = 0; nf < 8; ++nf)
                acc[nf] = __builtin_amdgcn_mfma_f32_16x16x32_bf16(afr[ks], bfr[ks][nf], acc[nf], 0, 0, 0);
        #pragma unroll
        for (int nf = 0; nf < 8; ++nf) {
            #pragma unroll
            for (int r = 0; r < 4; ++r) {
                int row = m0 + qa * 4 + r;
                if (row < N) {
                    float v = acc[nf][r] + bi[nf];
                    if (MODE == 0) v = fmaxf(v, 0.f);
                    else           v = fmaxf(fmaf(gg[nf] * v, INVSTD, be_[nf]), 0.f);
                    if (EBF)       v += ef[nf];
                    if (OUT16)
                        out[(size_t)row * HDIM + nf * 16 + ra] = f2h(v);
                    else
                        out[(size_t)row * HDIM + nf * 16 + ra] = (ushort_t)f2bf(v);
                }
            }
        }
    }
}

// ------------- pooling: segmented reduction over sorted batch (fp16 in) -------------
#define PCHUNK 256
#define PWIN 4
__global__ __launch_bounds__(256) void k_pool2(const ushort_t* __restrict__ hh,
                                               const int* __restrict__ batch,
                                               float* pooled, int N) {
    __shared__ float acc[PWIN][HDIM];
    int n0 = blockIdx.x * PCHUNK;
    if (n0 >= N) return;
    int n1 = min(n0 + PCHUNK, N);
    int g0 = batch[n0];
    int g1 = batch[n1 - 1];
    for (int i = threadIdx.x; i < PWIN * HDIM; i += 256) ((float*)acc)[i] = 0.f;
    __syncthreads();

    int grp = threadIdx.x >> 5;
    int q = threadIdx.x & 31;
    float4 racc = make_float4(0.f, 0.f, 0.f, 0.f);
    int gcur = g0;
    for (int n = n0 + grp; n < n1; n += 8) {
        int g = batch[n];
        if (g != gcur) {
            int w = gcur - g0;
            float* p = (w < PWIN) ? &acc[w][q * 4] : (pooled + gcur * HDIM + q * 4);
            atomicAdd(p + 0, racc.x); atomicAdd(p + 1, racc.y);
            atomicAdd(p + 2, racc.z); atomicAdd(p + 3, racc.w);
            racc = make_float4(0.f, 0.f, 0.f, 0.f);
            gcur = g;
        }
        uint2 u = ((const uint2*)(hh + (size_t)n * HDIM))[q];
        h16x2 f0 = u2h(u.x), f1 = u2h(u.y);
        racc.x += (float)f0[0];
        racc.y += (float)f0[1];
        racc.z += (float)f1[0];
        racc.w += (float)f1[1];
    }
    {
        int w = gcur - g0;
        float* p = (w < PWIN) ? &acc[w][q * 4] : (pooled + gcur * HDIM + q * 4);
        atomicAdd(p + 0, racc.x); atomicAdd(p + 1, racc.y);
        atomicAdd(p + 2, racc.z); atomicAdd(p + 3, racc.w);
    }
    __syncthreads();

    int span = min(g1 - g0 + 1, PWIN);
    for (int i = threadIdx.x; i < span * HDIM; i += 256) {
        int w = i >> 7, f = i & 127;
        float v = acc[w][f];
        if (v != 0.f) atomicAdd(pooled + (g0 + w) * HDIM + f, v);
    }
}

// ------------- classifier (count fused via binary search) -------------
__global__ void k_classify(const float* __restrict__ pooled, const int* __restrict__ batch,
                           const float* __restrict__ cw1, const float* __restrict__ cb1,
                           const float* __restrict__ cw2, const float* __restrict__ cb2,
                           float* __restrict__ out, int N) {
    __shared__ float p[HDIM];
    int g = blockIdx.x, j = threadIdx.x;
    int lo = 0, hi = N;
    while (lo < hi) { int m = (lo + hi) >> 1; if (batch[m] < g) lo = m + 1; else hi = m; }
    int lo2 = lo, hi2 = N;
    while (lo2 < hi2) { int m = (lo2 + hi2) >> 1; if (batch[m] < g + 1) lo2 = m + 1; else hi2 = m; }
    float c = fmaxf((float)(lo2 - lo), 1.f);
    p[j]      = pooled[g * HDIM + j] / c;
    p[j + 64] = pooled[g * HDIM + j + 64] / c;
    __syncthreads();
    float acc = cb1[j];
    #pragma unroll 4
    for (int k = 0; k < HDIM; ++k) acc = fmaf(p[k], cw1[k * 64 + j], acc);
    acc = fmaxf(acc, 0.f);
    float v = acc * cw2[j];
    #pragma unroll
    for (int off = 32; off > 0; off >>= 1) v += __shfl_down(v, off, 64);
    if (j == 0) out[g] = 1.f / (1.f + expf(-(v + cb2[0])));
}

static inline size_t align_up(size_t v, size_t a) { return (v + a - 1) & ~(a - 1); }

extern "C" void kernel_launch(void* const* d_in, const int* in_sizes, int n_in,
                              void* d_out, int out_size, void* d_ws, size_t ws_size,
                              hipStream_t stream) {
    const float* x      = (const float*)d_in[0];
    const int*   ei     = (const int*)d_in[1];
    const float* eattr  = (const float*)d_in[2];
    const int*   batch  = (const int*)d_in[3];
    const float* enc_w  = (const float*)d_in[4];
    const float* enc_b  = (const float*)d_in[5];
    const float* eenc_w = (const float*)d_in[6];
    const float* eenc_b = (const float*)d_in[7];
    const float* eps    = (const float*)d_in[8];
    const float* w1     = (const float*)d_in[9];
    const float* b1     = (const float*)d_in[10];
    const float* w2     = (const float*)d_in[11];
    const float* b2     = (const float*)d_in[12];
    const float* gamma  = (const float*)d_in[13];
    const float* beta   = (const float*)d_in[14];
    const float* cw1    = (const float*)d_in[15];
    const float* cb1    = (const float*)d_in[16];
    const float* cw2    = (const float*)d_in[17];
    const float* cb2    = (const float*)d_in[18];

    int N = in_sizes[0];          // 100000
    int E = in_sizes[2];          // 1600000

    int nb = (N + BKN - 1) / BKN;           // 196 coarse buckets (<=256)
    int nblk = (E + EPB - 1) / EPB;         // 391 pass-A/B blocks

    char* wsb = (char*)d_ws;
    size_t off = 0;
    ushort_t* hh  = (ushort_t*)(wsb + off); off = align_up(off + (size_t)N * HDIM * 2, 256);
    ushort_t* zb  = (ushort_t*)(wsb + off); off = align_up(off + (size_t)N * HDIM * 2, 256);
    ushort_t* wtg = (ushort_t*)(wsb + off); off = align_up(off + (size_t)4 * WSLOT * 2, 256);
    float* pooled = (float*)(wsb + off);    off = align_up(off + NGRAPH * HDIM * 4, 256);
    int*   btot   = (int*)(wsb + off);      off = align_up(off + (size_t)(nb + 1) * 4, 256);
    int*   segs   = (int*)(wsb + off);      off = align_up(off + (size_t)(nb + 1) * 4, 256);
    int*   cursor = (int*)(wsb + off);      off = align_up(off + (size_t)nb * 4, 256);
    int*   rs     = (int*)(wsb + off);      off = align_up(off + (size_t)(N + 1) * 4, 256);
    int2*  ebuf   = (int2*)(wsb + off);     off = align_up(off + (size_t)E * 8, 256);
    int2*  epack  = (int2*)(wsb + off);     off = align_up(off + (size_t)E * 8, 256);

    // CSR build (bucket counting sort) + weight prep
    hipMemsetAsync(btot, 0, (size_t)(nb + 1) * 4, stream);
    hipMemsetAsync(cursor, 0, (size_t)nb * 4, stream);
    k_cnt<<<nblk, 256, 0, stream>>>(ei, btot, nb, E);
    k_prepw<<<256, 256, 0, stream>>>(w1, w2, wtg);
    k_bscan<<<1, 256, 0, stream>>>(btot, segs, nb, E);
    k_place0<<<nblk, 256, 0, stream>>>(ei, eattr, segs, cursor, ebuf, nb, E);
    k_fine<<<nb, 256, 0, stream>>>(ebuf, segs, epack, rs, nb, N, E);

    hipMemsetAsync(pooled, 0, NGRAPH * HDIM * sizeof(float), stream);
    k_encode<<<2048, 256, 0, stream>>>(x, enc_w, enc_b, eenc_b, hh, N);

    int gblocks = (N + 255) / 256;
    int ablocks = (N * 64 + 255) / 256;

    // layer 0 (gather tables carry +eenc_b; agg corrects self-term)
    k_agg<<<ablocks, 256, 0, stream>>>(hh, rs, epack, eenc_w, eenc_b, eps + 0, zb, N);
    k_gemm<0,0,0><<<gblocks, 256, 0, stream>>>(zb, wtg + 0 * WSLOT, b1, nullptr, nullptr,
                                               nullptr, zb, N);
    k_gemm<1,1,1><<<gblocks, 256, 0, stream>>>(zb, wtg + 1 * WSLOT, b2, gamma, beta,
                                               eenc_b, hh, N);
    // layer 1 (final output: fp16 table for pooling)
    k_agg<<<ablocks, 256, 0, stream>>>(hh, rs, epack, eenc_w, eenc_b, eps + 1, zb, N);
    k_gemm<0,0,0><<<gblocks, 256, 0, stream>>>(zb, wtg + 2 * WSLOT, b1 + HDIM, nullptr, nullptr,
                                               nullptr, zb, N);
    k_gemm<1,0,1><<<gblocks, 256, 0, stream>>>(zb, wtg + 3 * WSLOT, b2 + HDIM, gamma + HDIM,
                                               beta + HDIM, nullptr, hh, N);

    k_pool2<<<(N + PCHUNK - 1) / PCHUNK, 256, 0, stream>>>(hh, batch, pooled, N);
    k_classify<<<NGRAPH, 64, 0, stream>>>(pooled, batch, cw1, cb1, cw2, cb2, (float*)d_out, N);
}

// Round 20
// 281.506 us; speedup vs baseline: 1.0977x; 1.0977x over previous
//
#include <hip/hip_runtime.h>

#define HDIM 128
#define NGRAPH 64
#define INVSTD 0.99999500003749972f   // 1/sqrt(1+1e-5)
#define WTPAD 136
#define WSLOT (128 * WTPAD)
#define BKN 512                        // nodes per bucket (power of 2)
#define CAP 16384                      // edge capacity per bucket (2x expected max)
#define EPB 4096                       // edges per pass-B block

typedef unsigned short ushort_t;
typedef unsigned int uint_t;
typedef unsigned char uchar_t;
typedef __attribute__((ext_vector_type(8))) short bf16x8;   // 8 bf16 = 4 VGPR
typedef __attribute__((ext_vector_type(4))) float f32x4;
typedef __attribute__((ext_vector_type(2))) float f32x2;
typedef __attribute__((ext_vector_type(2))) _Float16 h16x2;
typedef __attribute__((ext_vector_type(2))) __fp16 fp16x2;

__device__ __forceinline__ float bf2f(uint_t u) {            // low 16 bits
    return __int_as_float((int)(u << 16));
}
__device__ __forceinline__ uint_t f2bf(float f) {            // RNE
    uint_t x = __float_as_uint(f);
    return (x + 0x7FFFu + ((x >> 16) & 1u)) >> 16;
}
__device__ __forceinline__ uint_t pack2(float a, float b) {
    return f2bf(a) | (f2bf(b) << 16);
}
__device__ __forceinline__ uint_t h2u(h16x2 h) {
    union { h16x2 h; uint_t u; } x; x.h = h; return x.u;
}
__device__ __forceinline__ h16x2 u2h(uint_t u) {
    union { h16x2 h; uint_t u; } x; x.u = u; return x.h;
}
__device__ __forceinline__ uint_t packh2(float a, float b) {
    h16x2 v; v[0] = (_Float16)a; v[1] = (_Float16)b; return h2u(v);
}
__device__ __forceinline__ ushort_t f2h(float f) {
    union { _Float16 h; ushort_t u; } x; x.h = (_Float16)f; return x.u;
}
__device__ __forceinline__ h16x2 pkrtz(float a, float b) {   // v_cvt_pkrtz_f16_f32
    union { fp16x2 f; h16x2 h; } x;
    x.f = __builtin_amdgcn_cvt_pkrtz(a, b);
    return x.h;
}
__device__ __forceinline__ uint_t pkmax0(uint_t x) {         // packed relu: v_pk_max_f16(x, 0)
    uint_t r, z = 0;
    asm("v_pk_max_f16 %0, %1, %2" : "=v"(r) : "v"(x), "v"(z));
    return r;
}
__device__ __forceinline__ uint_t pack4fp8(float a, float b, float c, float d) {
    int v = __builtin_amdgcn_cvt_pk_fp8_f32(a, b, 0, false);
    v = __builtin_amdgcn_cvt_pk_fp8_f32(c, d, v, true);
    return (uint_t)v;
}

// ---- encode: table T = x*ew + enc_b + eenc_b; hh = fp16(T), hq = fp8(T)
__global__ void k_encode(const float* __restrict__ x, const float* __restrict__ ew,
                         const float* __restrict__ enb, const float* __restrict__ ebe,
                         ushort_t* __restrict__ hh, uchar_t* __restrict__ hq, int N) {
    int tid = blockIdx.x * blockDim.x + threadIdx.x;
    int stride = gridDim.x * blockDim.x;
    int q = tid & 15;
    float4 wa = ((const float4*)ew)[2 * q];
    float4 wb = ((const float4*)ew)[2 * q + 1];
    float4 ba = ((const float4*)enb)[2 * q];
    float4 bb = ((const float4*)enb)[2 * q + 1];
    float4 ea = ((const float4*)ebe)[2 * q];
    float4 eb2 = ((const float4*)ebe)[2 * q + 1];
    ba.x += ea.x; ba.y += ea.y; ba.z += ea.z; ba.w += ea.w;
    bb.x += eb2.x; bb.y += eb2.y; bb.z += eb2.z; bb.w += eb2.w;
    int total = N * 16;
    for (int t = tid; t < total; t += stride) {
        int n = t >> 4;
        float xv = x[n];
        float v0 = fmaf(xv, wa.x, ba.x), v1 = fmaf(xv, wa.y, ba.y);
        float v2 = fmaf(xv, wa.z, ba.z), v3 = fmaf(xv, wa.w, ba.w);
        float v4 = fmaf(xv, wb.x, bb.x), v5 = fmaf(xv, wb.y, bb.y);
        float v6 = fmaf(xv, wb.z, bb.z), v7 = fmaf(xv, wb.w, bb.w);
        uint4 o;
        o.x = packh2(v0, v1); o.y = packh2(v2, v3);
        o.z = packh2(v4, v5); o.w = packh2(v6, v7);
        ((uint4*)(hh + (size_t)n * HDIM))[q] = o;
        uint2 o8;
        o8.x = pack4fp8(v0, v1, v2, v3);
        o8.y = pack4fp8(v4, v5, v6, v7);
        ((uint2*)(hq + (size_t)n * HDIM))[q] = o8;
    }
}

// ---- weight prep: wtg[slot][n*WTPAD+k] = bf16(W_slot[k][n]); slots {w1_0,w2_0,w1_1,w2_1}
__global__ void k_prepw(const float* __restrict__ w1, const float* __restrict__ w2,
                        ushort_t* __restrict__ wtg) {
    int t = blockIdx.x * 256 + threadIdx.x;
    if (t >= 4 * 16384) return;
    int w = t >> 14, idx = t & 16383;
    int k = idx >> 7, n = idx & 127;
    const float* src = ((w & 1) ? w2 : w1) + (size_t)(w >> 1) * 16384;
    wtg[(size_t)w * WSLOT + n * WTPAD + k] = (ushort_t)f2bf(src[idx]);
}

// =============== CSR build: 2-kernel bucket sort with capacity-padded buckets ===============
__global__ __launch_bounds__(256) void k_place0(const int* __restrict__ ei,
                                                const float* __restrict__ attr,
                                                int* cursor, int2* __restrict__ ebuf,
                                                int nb, int E) {
    __shared__ int hist[256];
    __shared__ int basev[256];
    hist[threadIdx.x] = 0;
    __syncthreads();
    int e0 = blockIdx.x * EPB;
    for (int i = threadIdx.x; i < EPB; i += 256) {
        int e = e0 + i;
        if (e < E) atomicAdd(&hist[ei[E + e] / BKN], 1);
    }
    __syncthreads();
    {
        int c = hist[threadIdx.x];
        basev[threadIdx.x] = (threadIdx.x < nb && c > 0) ? atomicAdd(&cursor[threadIdx.x], c) : 0;
        hist[threadIdx.x] = 0;          // reuse as local rank cursor
    }
    __syncthreads();
    for (int i = threadIdx.x; i < EPB; i += 256) {
        int e = e0 + i;
        if (e < E) {
            int s = ei[e], d = ei[E + e];
            float a = attr[e];
            int b = d / BKN;
            int r = atomicAdd(&hist[b], 1);
            ebuf[(size_t)b * CAP + basev[b] + r] = make_int2(s | ((d & (BKN - 1)) << 17),
                                                             (int)packh2(a, a));
        }
    }
}

// Pass C: one block per bucket; cursor[b] = bucket count. Writes per-node {start,deg}
// and places edges at exact CSR slots within the bucket's padded window.
__global__ __launch_bounds__(256) void k_fine(const int2* __restrict__ ebuf,
                                              const int* __restrict__ bcnt,
                                              int2* __restrict__ epack, int2* __restrict__ rsse,
                                              int N) {
    __shared__ int hist[BKN];
    __shared__ int cur[BKN];
    __shared__ int psum[256];
    int b = blockIdx.x;
    int base = b * CAP;
    int cnt = bcnt[b];
    int d0 = b * BKN;
    int nd = min(BKN, N - d0);
    for (int i = threadIdx.x; i < BKN; i += 256) hist[i] = 0;
    __syncthreads();
    for (int e = base + threadIdx.x; e < base + cnt; e += 256)
        atomicAdd(&hist[(uint_t)ebuf[e].x >> 17], 1);
    __syncthreads();
    int h0 = hist[2 * threadIdx.x], h1 = hist[2 * threadIdx.x + 1];
    psum[threadIdx.x] = h0 + h1;
    __syncthreads();
    #pragma unroll
    for (int off = 1; off < 256; off <<= 1) {
        int u = (threadIdx.x >= off) ? psum[threadIdx.x - off] : 0;
        __syncthreads();
        psum[threadIdx.x] += u;
        __syncthreads();
    }
    int pb = psum[threadIdx.x] - (h0 + h1);
    cur[2 * threadIdx.x] = pb;
    cur[2 * threadIdx.x + 1] = pb + h0;
    __syncthreads();
    for (int i = threadIdx.x; i < nd; i += 256)
        rsse[d0 + i] = make_int2(base + cur[i], hist[i]);
    __syncthreads();
    for (int e = base + threadIdx.x; e < base + cnt; e += 256) {
        int2 rec = ebuf[e];
        int dl = (uint_t)rec.x >> 17;
        int r = atomicAdd(&cur[dl], 1);
        epack[base + r] = make_int2(rec.x & 0x1FFFF, rec.y);
    }
}

// ------- aggregation: one wave/node, 16 lanes/edge, fp8 gathers, packed-fp16 math -------
__device__ __forceinline__ void acc_edge(h16x2 acc[4], const uint2& u, h16x2 at2,
                                         const h16x2 w2[4]) {
    f32x2 p0 = __builtin_amdgcn_cvt_pk_f32_fp8(u.x, false);
    f32x2 p1 = __builtin_amdgcn_cvt_pk_f32_fp8(u.x, true);
    f32x2 p2 = __builtin_amdgcn_cvt_pk_f32_fp8(u.y, false);
    f32x2 p3 = __builtin_amdgcn_cvt_pk_f32_fp8(u.y, true);
    h16x2 h0 = pkrtz(p0[0], p0[1]);
    h16x2 h1 = pkrtz(p1[0], p1[1]);
    h16x2 h2 = pkrtz(p2[0], p2[1]);
    h16x2 h3 = pkrtz(p3[0], p3[1]);
    acc[0] += u2h(pkmax0(h2u(at2 * w2[0] + h0)));
    acc[1] += u2h(pkmax0(h2u(at2 * w2[1] + h1)));
    acc[2] += u2h(pkmax0(h2u(at2 * w2[2] + h2)));
    acc[3] += u2h(pkmax0(h2u(at2 * w2[3] + h3)));
}

__global__ __launch_bounds__(256) void k_agg(
    const uchar_t* __restrict__ hq, const ushort_t* __restrict__ hh,
    const int2* __restrict__ rsse, const int2* __restrict__ epack,
    const float* __restrict__ ew, const float* __restrict__ ebv,
    const float* __restrict__ epsp, ushort_t* __restrict__ zb, int N) {
    int wave = (blockIdx.x * 256 + threadIdx.x) >> 6;
    if (wave >= N) return;
    int lane = threadIdx.x & 63;
    int p = lane >> 4;          // quarter-wave: edges j ≡ p (mod 4)
    int q = lane & 15;          // features 8q..8q+7
    int n = wave;
    int2 se = rsse[n];
    int beg = se.x, cntE = se.y;
    float4 wa = ((const float4*)ew)[2 * q], wb = ((const float4*)ew)[2 * q + 1];
    h16x2 w2[4];
    w2[0] = u2h(packh2(wa.x, wa.y));
    w2[1] = u2h(packh2(wa.z, wa.w));
    w2[2] = u2h(packh2(wb.x, wb.y));
    w2[3] = u2h(packh2(wb.z, wb.w));

    h16x2 acc[4], acc2[4];
    #pragma unroll
    for (int k = 0; k < 4; ++k) { acc[k] = u2h(0u); acc2[k] = u2h(0u); }
    int j = p;
    for (; j + 4 < cntE; j += 8) {
        int2 e1 = epack[beg + j];
        int2 e2 = epack[beg + j + 4];
        uint2 u1 = *(const uint2*)(hq + (size_t)e1.x * HDIM + q * 8);
        uint2 u2v = *(const uint2*)(hq + (size_t)e2.x * HDIM + q * 8);
        acc_edge(acc,  u1, u2h((uint_t)e1.y), w2);
        acc_edge(acc2, u2v, u2h((uint_t)e2.y), w2);
    }
    if (j < cntE) {
        int2 e1 = epack[beg + j];
        uint2 u1 = *(const uint2*)(hq + (size_t)e1.x * HDIM + q * 8);
        acc_edge(acc, u1, u2h((uint_t)e1.y), w2);
    }
    #pragma unroll
    for (int k = 0; k < 4; ++k) {
        h16x2 c = acc[k] + acc2[k];
        c += u2h((uint_t)__shfl_xor((int)h2u(c), 16));
        c += u2h((uint_t)__shfl_xor((int)h2u(c), 32));
        acc[k] = c;
    }
    if (p == 0) {
        float sc = 1.f + epsp[0];
        float4 ba = ((const float4*)ebv)[2 * q], bb = ((const float4*)ebv)[2 * q + 1];
        uint4 u = *(const uint4*)(hh + (size_t)n * HDIM + q * 8);
        h16x2 t0 = u2h(u.x), t1 = u2h(u.y), t2 = u2h(u.z), t3 = u2h(u.w);
        uint4 ob;
        ob.x = pack2(fmaf(sc, (float)t0[0], (float)acc[0][0]) - sc * ba.x,
                     fmaf(sc, (float)t0[1], (float)acc[0][1]) - sc * ba.y);
        ob.y = pack2(fmaf(sc, (float)t1[0], (float)acc[1][0]) - sc * ba.z,
                     fmaf(sc, (float)t1[1], (float)acc[1][1]) - sc * ba.w);
        ob.z = pack2(fmaf(sc, (float)t2[0], (float)acc[2][0]) - sc * bb.x,
                     fmaf(sc, (float)t2[1], (float)acc[2][1]) - sc * bb.y);
        ob.w = pack2(fmaf(sc, (float)t3[0], (float)acc[3][0]) - sc * bb.z,
                     fmaf(sc, (float)t3[1], (float)acc[3][1]) - sc * bb.w);
        *(uint4*)(zb + (size_t)n * HDIM + q * 8) = ob;
    }
}

// ------------- MFMA GEMM: out = epilogue(A @ W + bias), 256 rows/block -------------
// MODE 0: relu, bf16 out.  MODE 1: BN+relu.  EBF: +eenc_b.  OUT16: fp16 out.  WQ: fp8 copy.
template<int MODE, int EBF, int OUT16, int WQ>
__global__ __launch_bounds__(256) void k_gemm(
    const ushort_t* __restrict__ A, const ushort_t* __restrict__ WT,
    const float* __restrict__ bias, const float* __restrict__ gam,
    const float* __restrict__ bet, const float* __restrict__ ebe,
    ushort_t* __restrict__ out, uchar_t* __restrict__ outq, int N) {
    __shared__ ushort_t wt[128 * WTPAD];
    int tid = threadIdx.x;
    #pragma unroll
    for (int i = 0; i < 9; ++i) {           // 128*136/8 = 2176 bf16x8 chunks
        int c = i * 256 + tid;
        if (c < 2176) ((bf16x8*)wt)[c] = ((const bf16x8*)WT)[c];
    }
    __syncthreads();

    int wid = tid >> 6, lane = tid & 63;
    int ra = lane & 15, qa = lane >> 4;

    bf16x8 bfr[4][8];
    #pragma unroll
    for (int ks = 0; ks < 4; ++ks)
        #pragma unroll
        for (int nf = 0; nf < 8; ++nf)
            bfr[ks][nf] = *(const bf16x8*)&wt[(nf * 16 + ra) * WTPAD + ks * 32 + qa * 8];

    float bi[8], gg[8], be_[8], ef[8];
    #pragma unroll
    for (int nf = 0; nf < 8; ++nf) {
        int col = nf * 16 + ra;
        bi[nf] = bias[col];
        if (MODE == 1) { gg[nf] = gam[col]; be_[nf] = bet[col]; }
        if (EBF)       { ef[nf] = ebe[col]; }
    }

    bf16x8 azero;
    #pragma unroll
    for (int j = 0; j < 8; ++j) azero[j] = 0;

    #pragma unroll
    for (int it = 0; it < 4; ++it) {
        int m0 = blockIdx.x * 256 + it * 64 + wid * 16;
        int mr = m0 + ra;
        bf16x8 afr[4];
        #pragma unroll
        for (int ks = 0; ks < 4; ++ks)
            afr[ks] = (mr < N) ? *(const bf16x8*)&A[(size_t)mr * HDIM + ks * 32 + qa * 8]
                               : azero;
        f32x4 acc[8];
        #pragma unroll
        for (int nf = 0; nf < 8; ++nf)
            #pragma unroll
            for (int j = 0; j < 4; ++j) acc[nf][j] = 0.f;
        #pragma unroll
        for (int ks = 0; ks < 4; ++ks)
            #pragma unroll
            for (int nf = 0; nf < 8; ++nf)
                acc[nf] = __builtin_amdgcn_mfma_f32_16x16x32_bf16(afr[ks], bfr[ks][nf], acc[nf], 0, 0, 0);
        #pragma unroll
        for (int nf = 0; nf < 8; ++nf) {
            #pragma unroll
            for (int r = 0; r < 4; ++r) {
                int row = m0 + qa * 4 + r;
                if (row < N) {
                    float v = acc[nf][r] + bi[nf];
                    if (MODE == 0) v = fmaxf(v, 0.f);
                    else           v = fmaxf(fmaf(gg[nf] * v, INVSTD, be_[nf]), 0.f);
                    if (EBF)       v += ef[nf];
                    if (OUT16)
                        out[(size_t)row * HDIM + nf * 16 + ra] = f2h(v);
                    else
                        out[(size_t)row * HDIM + nf * 16 + ra] = (ushort_t)f2bf(v);
                    if (WQ)
                        outq[(size_t)row * HDIM + nf * 16 + ra] =
                            (uchar_t)(__builtin_amdgcn_cvt_pk_fp8_f32(v, 0.f, 0, false) & 0xFF);
                }
            }
        }
    }
}

// ------------- pooling: segmented reduction over sorted batch (fp16 in) -------------
#define PCHUNK 256
#define PWIN 4
__global__ __launch_bounds__(256) void k_pool2(const ushort_t* __restrict__ hh,
                                               const int* __restrict__ batch,
                                               float* pooled, int N) {
    __shared__ float acc[PWIN][HDIM];
    int n0 = blockIdx.x * PCHUNK;
    if (n0 >= N) return;
    int n1 = min(n0 + PCHUNK, N);
    int g0 = batch[n0];
    int g1 = batch[n1 - 1];
    for (int i = threadIdx.x; i < PWIN * HDIM; i += 256) ((float*)acc)[i] = 0.f;
    __syncthreads();

    int grp = threadIdx.x >> 5;
    int q = threadIdx.x & 31;
    float4 racc = make_float4(0.f, 0.f, 0.f, 0.f);
    int gcur = g0;
    for (int n = n0 + grp; n < n1; n += 8) {
        int g = batch[n];
        if (g != gcur) {
            int w = gcur - g0;
            float* p = (w < PWIN) ? &acc[w][q * 4] : (pooled + gcur * HDIM + q * 4);
            atomicAdd(p + 0, racc.x); atomicAdd(p + 1, racc.y);
            atomicAdd(p + 2, racc.z); atomicAdd(p + 3, racc.w);
            racc = make_float4(0.f, 0.f, 0.f, 0.f);
            gcur = g;
        }
        uint2 u = ((const uint2*)(hh + (size_t)n * HDIM))[q];
        h16x2 f0 = u2h(u.x), f1 = u2h(u.y);
        racc.x += (float)f0[0];
        racc.y += (float)f0[1];
        racc.z += (float)f1[0];
        racc.w += (float)f1[1];
    }
    {
        int w = gcur - g0;
        float* p = (w < PWIN) ? &acc[w][q * 4] : (pooled + gcur * HDIM + q * 4);
        atomicAdd(p + 0, racc.x); atomicAdd(p + 1, racc.y);
        atomicAdd(p + 2, racc.z); atomicAdd(p + 3, racc.w);
    }
    __syncthreads();

    int span = min(g1 - g0 + 1, PWIN);
    for (int i = threadIdx.x; i < span * HDIM; i += 256) {
        int w = i >> 7, f = i & 127;
        float v = acc[w][f];
        if (v != 0.f) atomicAdd(pooled + (g0 + w) * HDIM + f, v);
    }
}

// ------------- classifier (count fused via binary search) -------------
__global__ void k_classify(const float* __restrict__ pooled, const int* __restrict__ batch,
                           const float* __restrict__ cw1, const float* __restrict__ cb1,
                           const float* __restrict__ cw2, const float* __restrict__ cb2,
                           float* __restrict__ out, int N) {
    __shared__ float p[HDIM];
    int g = blockIdx.x, j = threadIdx.x;
    int lo = 0, hi = N;
    while (lo < hi) { int m = (lo + hi) >> 1; if (batch[m] < g) lo = m + 1; else hi = m; }
    int lo2 = lo, hi2 = N;
    while (lo2 < hi2) { int m = (lo2 + hi2) >> 1; if (batch[m] < g + 1) lo2 = m + 1; else hi2 = m; }
    float c = fmaxf((float)(lo2 - lo), 1.f);
    p[j]      = pooled[g * HDIM + j] / c;
    p[j + 64] = pooled[g * HDIM + j + 64] / c;
    __syncthreads();
    float acc = cb1[j];
    #pragma unroll 4
    for (int k = 0; k < HDIM; ++k) acc = fmaf(p[k], cw1[k * 64 + j], acc);
    acc = fmaxf(acc, 0.f);
    float v = acc * cw2[j];
    #pragma unroll
    for (int off = 32; off > 0; off >>= 1) v += __shfl_down(v, off, 64);
    if (j == 0) out[g] = 1.f / (1.f + expf(-(v + cb2[0])));
}

static inline size_t align_up(size_t v, size_t a) { return (v + a - 1) & ~(a - 1); }

extern "C" void kernel_launch(void* const* d_in, const int* in_sizes, int n_in,
                              void* d_out, int out_size, void* d_ws, size_t ws_size,
                              hipStream_t stream) {
    const float* x      = (const float*)d_in[0];
    const int*   ei     = (const int*)d_in[1];
    const float* eattr  = (const float*)d_in[2];
    const int*   batch  = (const int*)d_in[3];
    const float* enc_w  = (const float*)d_in[4];
    const float* enc_b  = (const float*)d_in[5];
    const float* eenc_w = (const float*)d_in[6];
    const float* eenc_b = (const float*)d_in[7];
    const float* eps    = (const float*)d_in[8];
    const float* w1     = (const float*)d_in[9];
    const float* b1     = (const float*)d_in[10];
    const float* w2     = (const float*)d_in[11];
    const float* b2     = (const float*)d_in[12];
    const float* gamma  = (const float*)d_in[13];
    const float* beta   = (const float*)d_in[14];
    const float* cw1    = (const float*)d_in[15];
    const float* cb1    = (const float*)d_in[16];
    const float* cw2    = (const float*)d_in[17];
    const float* cb2    = (const float*)d_in[18];

    int N = in_sizes[0];          // 100000
    int E = in_sizes[2];          // 1600000

    int nb = (N + BKN - 1) / BKN;           // 196 coarse buckets (<=256)
    int nblk = (E + EPB - 1) / EPB;         // 391 pass-B blocks

    char* wsb = (char*)d_ws;
    size_t off = 0;
    ushort_t* hh  = (ushort_t*)(wsb + off); off = align_up(off + (size_t)N * HDIM * 2, 256);
    uchar_t*  hq  = (uchar_t*)(wsb + off);  off = align_up(off + (size_t)N * HDIM, 256);
    ushort_t* zb  = (ushort_t*)(wsb + off); off = align_up(off + (size_t)N * HDIM * 2, 256);
    ushort_t* wtg = (ushort_t*)(wsb + off); off = align_up(off + (size_t)4 * WSLOT * 2, 256);
    float* pooled = (float*)(wsb + off);    off = align_up(off + NGRAPH * HDIM * 4, 256);
    int*   cursor = (int*)(wsb + off);      off = align_up(off + (size_t)nb * 4, 256);
    int2*  rsse   = (int2*)(wsb + off);     off = align_up(off + (size_t)N * 8, 256);
    int2*  ebuf   = (int2*)(wsb + off);     off = align_up(off + (size_t)nb * CAP * 8, 256);
    int2*  epack  = (int2*)(wsb + off);     off = align_up(off + (size_t)nb * CAP * 8, 256);

    // CSR build (2-kernel padded bucket sort) + weight prep
    hipMemsetAsync(cursor, 0, (size_t)nb * 4, stream);
    k_place0<<<nblk, 256, 0, stream>>>(ei, eattr, cursor, ebuf, nb, E);
    k_prepw<<<256, 256, 0, stream>>>(w1, w2, wtg);
    k_fine<<<nb, 256, 0, stream>>>(ebuf, cursor, epack, rsse, N);

    hipMemsetAsync(pooled, 0, NGRAPH * HDIM * sizeof(float), stream);
    k_encode<<<2048, 256, 0, stream>>>(x, enc_w, enc_b, eenc_b, hh, hq, N);

    int gblocks = (N + 255) / 256;
    int ablocks = (N * 64 + 255) / 256;

    // layer 0 (gather tables carry +eenc_b; agg corrects self-term)
    k_agg<<<ablocks, 256, 0, stream>>>(hq, hh, rsse, epack, eenc_w, eenc_b, eps + 0, zb, N);
    k_gemm<0,0,0,0><<<gblocks, 256, 0, stream>>>(zb, wtg + 0 * WSLOT, b1, nullptr, nullptr,
                                                 nullptr, zb, nullptr, N);
    k_gemm<1,1,1,1><<<gblocks, 256, 0, stream>>>(zb, wtg + 1 * WSLOT, b2, gamma, beta,
                                                 eenc_b, hh, hq, N);
    // layer 1 (final output: fp16 table for pooling)
    k_agg<<<ablocks, 256, 0, stream>>>(hq, hh, rsse, epack, eenc_w, eenc_b, eps + 1, zb, N);
    k_gemm<0,0,0,0><<<gblocks, 256, 0, stream>>>(zb, wtg + 2 * WSLOT, b1 + HDIM, nullptr, nullptr,
                                                 nullptr, zb, nullptr, N);
    k_gemm<1,0,1,0><<<gblocks, 256, 0, stream>>>(zb, wtg + 3 * WSLOT, b2 + HDIM, gamma + HDIM,
                                                 beta + HDIM, nullptr, hh, nullptr, N);

    k_pool2<<<(N + PCHUNK - 1) / PCHUNK, 256, 0, stream>>>(hh, batch, pooled, N);
    k_classify<<<NGRAPH, 64, 0, stream>>>(pooled, batch, cw1, cb1, cw2, cb2, (float*)d_out, N);
}